// Round 1
// baseline (4620.822 us; speedup 1.0000x reference)
//
#include <hip/hip_runtime.h>
#include <hip/hip_bf16.h>

// Problem: B=1024, F=1024, S=64, 64 recurrent steps.
// Restructuring:
//   base  = query @ Wq^T + b_ih + b_hh            (precomputed once, f32)
//   SW^T  = (support @ Wr^T)^T  [4096 x 64]       (precomputed once, bf16)
//   per step: attn = softmax(h @ support^T)
//             gates = [h_bf | attn_bf] @ [W_hh | SW^T]^T + base   (bf16 MFMA, K=1088)
//             LSTM pointwise -> h, c

typedef __attribute__((ext_vector_type(8))) __bf16 bf16x8;
typedef __attribute__((ext_vector_type(4))) float f32x4;

__device__ __forceinline__ ushort f2bf(float f) {
  union { float f; unsigned int u; } v; v.f = f;
  unsigned int u = v.u;
  u += 0x7FFFu + ((u >> 16) & 1u);   // round-to-nearest-even
  return (ushort)(u >> 16);
}

__device__ __forceinline__ void async16(ushort* lds, const ushort* g) {
  __builtin_amdgcn_global_load_lds(
      (const __attribute__((address_space(1))) void*)g,
      (__attribute__((address_space(3))) void*)lds, 16, 0, 0);
}

// ---------------- precompute: casts, bias sum, h/c init --------------------
__global__ __launch_bounds__(256) void prep_kernel(
    const float* __restrict__ query, const float* __restrict__ W_ih,
    const float* __restrict__ W_hh, const float* __restrict__ b_ih,
    const float* __restrict__ b_hh,
    ushort* __restrict__ q_bf, ushort* __restrict__ Wq_bf,
    ushort* __restrict__ Wcomb, float* __restrict__ bias_sum,
    float* __restrict__ h, float* __restrict__ c)
{
  int g = blockIdx.x * 256 + threadIdx.x;        // 0 .. 4M-1
  int n = g >> 10, k = g & 1023;
  Wq_bf[g] = f2bf(W_ih[(size_t)n * 2048 + k]);           // W_ih[:, :1024]
  Wcomb[(size_t)n * 1088 + k] = f2bf(W_hh[g]);           // W_hh
  if (g < 1024 * 1024) {
    float qv = query[g];
    q_bf[g] = f2bf(qv);
    h[g] = qv;          // h0 = query
    c[g] = 0.f;         // c0 = 0
  }
  if (g < 4096) bias_sum[g] = b_ih[g] + b_hh[g];
}

// ---------------- precompute: SW^T[n][s] = sum_k support[s][k]*Wr[n][k] ----
__global__ __launch_bounds__(256) void sw_kernel(
    const float* __restrict__ support, const float* __restrict__ W_ih,
    ushort* __restrict__ Wcomb)
{
  int g = blockIdx.x * 256 + threadIdx.x;        // 0..262143
  int n = g >> 6, s = g & 63;
  const float* sp = support + (size_t)s * 1024;
  const float* wp = W_ih + (size_t)n * 2048 + 1024;   // W_ih[:, 1024:2048]
  float acc = 0.f;
  for (int k = 0; k < 1024; k += 4) {
    float4 a = *(const float4*)&sp[k];
    float4 b = *(const float4*)&wp[k];
    acc += a.x * b.x + a.y * b.y + a.z * b.z + a.w * b.w;
  }
  Wcomb[(size_t)n * 1088 + 1024 + s] = f2bf(acc);
}

// ---------------- per-step: logits + softmax -> X = [h_bf | attn_bf] ------
__global__ __launch_bounds__(256) void attn_kernel(
    const float* __restrict__ h, const float* __restrict__ support,
    ushort* __restrict__ X)
{
  __shared__ float hs[4][1024];
  __shared__ float lg[4][64];
  int t = threadIdx.x;
  int b0 = blockIdx.x * 4;
  // load 4 h rows into LDS, also cast to X[:, :1024]
  for (int r = 0; r < 4; r++) {
    float4 v = *(const float4*)&h[(size_t)(b0 + r) * 1024 + t * 4];
    *(float4*)&hs[r][t * 4] = v;
    ushort4 u; u.x = f2bf(v.x); u.y = f2bf(v.y); u.z = f2bf(v.z); u.w = f2bf(v.w);
    *(ushort4*)&X[(size_t)(b0 + r) * 1088 + t * 4] = u;
  }
  __syncthreads();
  // logits: thread (s = t>>2, q = t&3) sums quarter q of row-dot h[r] . support[s]
  int s = t >> 2, q = t & 3;
  const float* sp = support + (size_t)s * 1024 + q * 4;
  float a0 = 0, a1 = 0, a2 = 0, a3 = 0;
  for (int i = 0; i < 64; i++) {
    int k = i * 16;
    float4 sv = *(const float4*)&sp[k];
    int kk = k + q * 4;
    float4 h0 = *(const float4*)&hs[0][kk];
    float4 h1 = *(const float4*)&hs[1][kk];
    float4 h2 = *(const float4*)&hs[2][kk];
    float4 h3 = *(const float4*)&hs[3][kk];
    a0 += sv.x * h0.x + sv.y * h0.y + sv.z * h0.z + sv.w * h0.w;
    a1 += sv.x * h1.x + sv.y * h1.y + sv.z * h1.z + sv.w * h1.w;
    a2 += sv.x * h2.x + sv.y * h2.y + sv.z * h2.z + sv.w * h2.w;
    a3 += sv.x * h3.x + sv.y * h3.y + sv.z * h3.z + sv.w * h3.w;
  }
  a0 += __shfl_xor(a0, 1); a0 += __shfl_xor(a0, 2);
  a1 += __shfl_xor(a1, 1); a1 += __shfl_xor(a1, 2);
  a2 += __shfl_xor(a2, 1); a2 += __shfl_xor(a2, 2);
  a3 += __shfl_xor(a3, 1); a3 += __shfl_xor(a3, 2);
  if (q == 0) { lg[0][s] = a0; lg[1][s] = a1; lg[2][s] = a2; lg[3][s] = a3; }
  __syncthreads();
  // softmax over 64 (wave 0 only), write attn as bf16 to X[:, 1024:1088]
  if (t < 64) {
    for (int r = 0; r < 4; r++) {
      float v = lg[r][t];
      float m = v;
      for (int off = 32; off; off >>= 1) m = fmaxf(m, __shfl_xor(m, off));
      float e = __expf(v - m);
      float sm = e;
      for (int off = 32; off; off >>= 1) sm += __shfl_xor(sm, off);
      X[(size_t)(b0 + r) * 1088 + 1024 + t] = f2bf(e / sm);
    }
  }
}

// ---------------- bf16 MFMA GEMM: C[m][n] = sum_k A[m][k]*Bw[n][k] (+adds) -
// m97-style: 128x128 tile, BK=32, 4 waves, global_load_lds w16, linear LDS.
__global__ __launch_bounds__(256) void gemm_bt(
    const ushort* __restrict__ A, int lda,
    const ushort* __restrict__ Bw, int ldb,
    float* __restrict__ Cout,
    const float* __restrict__ addvec,   // [N] or null
    const float* __restrict__ addmat,   // [M][N] or null
    int K)
{
  __shared__ ushort As[128 * 32];
  __shared__ ushort Bs[128 * 32];
  const int t = threadIdx.x;
  const int m0 = blockIdx.x * 128;
  const int n0 = blockIdx.y * 128;
  const int w = t >> 6, l = t & 63;
  const int wm = (w >> 1) * 64, wn = (w & 1) * 64;
  // staging: thread t loads 8 bf16 (16B); two rows-groups per tile
  const int srow = t >> 2, scol = (t & 3) * 8;
  const ushort* ga0 = A + (size_t)(m0 + srow) * lda + scol;
  const ushort* ga1 = A + (size_t)(m0 + 64 + srow) * lda + scol;
  const ushort* gb0 = Bw + (size_t)(n0 + srow) * ldb + scol;
  const ushort* gb1 = Bw + (size_t)(n0 + 64 + srow) * ldb + scol;
  ushort* la0 = &As[t * 8];
  ushort* la1 = &As[2048 + t * 8];
  ushort* lb0 = &Bs[t * 8];
  ushort* lb1 = &Bs[2048 + t * 8];
  const int fr = l & 15, fk = (l >> 4) * 8;
  const ushort* pa = &As[(wm + fr) * 32 + fk];
  const ushort* pb = &Bs[(wn + fr) * 32 + fk];
  f32x4 acc[4][4] = {};
  for (int k0 = 0; k0 < K; k0 += 32) {
    async16(la0, ga0 + k0);
    async16(la1, ga1 + k0);
    async16(lb0, gb0 + k0);
    async16(lb1, gb1 + k0);
    __syncthreads();           // compiler drains vmcnt(0) before barrier
    bf16x8 af[4], bfr[4];
#pragma unroll
    for (int mi = 0; mi < 4; mi++) af[mi] = *(const bf16x8*)(pa + mi * 16 * 32);
#pragma unroll
    for (int ni = 0; ni < 4; ni++) bfr[ni] = *(const bf16x8*)(pb + ni * 16 * 32);
#pragma unroll
    for (int mi = 0; mi < 4; mi++)
#pragma unroll
      for (int ni = 0; ni < 4; ni++)
        acc[mi][ni] = __builtin_amdgcn_mfma_f32_16x16x32_bf16(af[mi], bfr[ni], acc[mi][ni], 0, 0, 0);
    __syncthreads();
  }
  // epilogue: D col = lane&15, row = (lane>>4)*4 + j   [m89/m91 mapping]
  const int fq = l >> 4;
  const int N = gridDim.y * 128;
  for (int mi = 0; mi < 4; mi++) {
    for (int ni = 0; ni < 4; ni++) {
      int col = n0 + wn + ni * 16 + fr;
      int row0 = m0 + wm + mi * 16 + fq * 4;
#pragma unroll
      for (int j = 0; j < 4; j++) {
        float v = acc[mi][ni][j];
        size_t off = (size_t)(row0 + j) * N + col;
        if (addvec) v += addvec[col];
        if (addmat) v += addmat[off];
        Cout[off] = v;
      }
    }
  }
}

// ---------------- per-step: LSTM pointwise ---------------------------------
__global__ __launch_bounds__(256) void lstm_kernel(
    const float* __restrict__ gates, const float* __restrict__ query,
    float* __restrict__ c, float* __restrict__ h_out)
{
  int gtid = blockIdx.x * 256 + threadIdx.x;
  int idx = gtid * 4;
  int b = idx >> 10, j = idx & 1023;
  const float* gp = gates + (size_t)b * 4096 + j;
  float4 gi = *(const float4*)gp;
  float4 gf = *(const float4*)(gp + 1024);
  float4 gg = *(const float4*)(gp + 2048);
  float4 go = *(const float4*)(gp + 3072);
  float4 cv = *(const float4*)&c[idx];
  float4 qv = *(const float4*)&query[idx];
  float4 cn, hn;
#define STEP(X) { \
    float si = 1.f / (1.f + __expf(-gi.X)); \
    float sf = 1.f / (1.f + __expf(-gf.X)); \
    float so = 1.f / (1.f + __expf(-go.X)); \
    float tg = tanhf(gg.X); \
    cn.X = sf * cv.X + si * tg; \
    hn.X = so * tanhf(cn.X) + qv.X; }
  STEP(x) STEP(y) STEP(z) STEP(w)
#undef STEP
  *(float4*)&c[idx] = cn;
  *(float4*)&h_out[idx] = hn;
}

extern "C" void kernel_launch(void* const* d_in, const int* in_sizes, int n_in,
                              void* d_out, int out_size, void* d_ws, size_t ws_size,
                              hipStream_t stream) {
  const float* query   = (const float*)d_in[0];
  const float* support = (const float*)d_in[1];
  const float* W_ih    = (const float*)d_in[2];
  const float* W_hh    = (const float*)d_in[3];
  const float* b_ih    = (const float*)d_in[4];
  const float* b_hh    = (const float*)d_in[5];
  float* out = (float*)d_out;

  char* ws = (char*)d_ws;
  size_t off = 0;
  auto alloc = [&](size_t bytes) {
    void* p = ws + off;
    off += (bytes + 255) & ~(size_t)255;
    return p;
  };
  ushort* q_bf  = (ushort*)alloc((size_t)1024 * 1024 * 2);
  ushort* Wq_bf = (ushort*)alloc((size_t)4096 * 1024 * 2);
  ushort* Wcomb = (ushort*)alloc((size_t)4096 * 1088 * 2);
  float*  bias  = (float*) alloc((size_t)4096 * 4);
  float*  base  = (float*) alloc((size_t)1024 * 4096 * 4);
  ushort* X     = (ushort*)alloc((size_t)1024 * 1088 * 2);
  float*  gates = (float*) alloc((size_t)1024 * 4096 * 4);
  float*  h     = (float*) alloc((size_t)1024 * 1024 * 4);
  float*  c     = (float*) alloc((size_t)1024 * 1024 * 4);

  prep_kernel<<<16384, 256, 0, stream>>>(query, W_ih, W_hh, b_ih, b_hh,
                                         q_bf, Wq_bf, Wcomb, bias, h, c);
  sw_kernel<<<1024, 256, 0, stream>>>(support, W_ih, Wcomb);
  // base = q_bf @ Wq^T + (b_ih + b_hh)
  gemm_bt<<<dim3(8, 32), 256, 0, stream>>>(q_bf, 1024, Wq_bf, 1024, base,
                                           bias, nullptr, 1024);
  for (int step = 0; step < 64; step++) {
    attn_kernel<<<256, 256, 0, stream>>>(h, support, X);
    gemm_bt<<<dim3(8, 32), 256, 0, stream>>>(X, 1088, Wcomb, 1088, gates,
                                             nullptr, base, 1088);
    float* hout = (step == 63) ? out : h;
    lstm_kernel<<<1024, 256, 0, stream>>>(gates, query, c, hout);
  }
}

// Round 2
// 2889.446 us; speedup vs baseline: 1.5992x; 1.5992x over previous
//
#include <hip/hip_runtime.h>
#include <hip/hip_bf16.h>

// B=1024, F=1024, S=64, 64 steps.
//   base   = q @ Wq_perm^T + (b_ih+b_hh)_perm     (once, f32, permuted cols)
//   Wcomb  = [W_hh | (support@Wr^T)^T]_perm rows  (once, bf16, K=1088)
//   step:  attn cols of X  = softmax(h_bf @ support^T)    (attn_kernel)
//          gates = X @ Wcomb^T + base  -> fused LSTM -> c, h(bf16 into Xnext)
// Weight-row permutation n' = (j>>4)*64 + gate*16 + (j&15) makes each wave's
// 4 n-frags = the 4 gates of the same 16 j-columns, same lane -> lane-local LSTM.

typedef __attribute__((ext_vector_type(8))) __bf16 bf16x8;
typedef __attribute__((ext_vector_type(4))) float f32x4;
typedef __attribute__((ext_vector_type(8))) unsigned short ushort8;

__device__ __forceinline__ ushort f2bf(float f) {
  union { float f; unsigned int u; } v; v.f = f;
  unsigned int u = v.u;
  u += 0x7FFFu + ((u >> 16) & 1u);   // RNE
  return (ushort)(u >> 16);
}
__device__ __forceinline__ float bf2f(ushort u) {
  union { float f; unsigned int u; } v; v.u = ((unsigned int)u) << 16; return v.f;
}
__device__ __forceinline__ float sigm_(float x) { return 1.f / (1.f + __expf(-x)); }
__device__ __forceinline__ float tanh_(float x) {
  x = fminf(15.f, fmaxf(-15.f, x));
  float e = __expf(2.f * x);
  return (e - 1.f) / (e + 1.f);
}
__device__ __forceinline__ void async16(ushort* lds, const ushort* g) {
  __builtin_amdgcn_global_load_lds(
      (const __attribute__((address_space(1))) void*)g,
      (__attribute__((address_space(3))) void*)lds, 16, 0, 0);
}
__device__ __forceinline__ int permrow(int n) {   // n = gate*1024 + j
  int g = n >> 10, j = n & 1023;
  return ((j >> 4) << 6) | (g << 4) | (j & 15);
}

// ---------------- precompute ------------------------------------------------
__global__ __launch_bounds__(256) void prep_kernel(
    const float* __restrict__ query, const float* __restrict__ support,
    const float* __restrict__ W_ih, const float* __restrict__ W_hh,
    const float* __restrict__ b_ih, const float* __restrict__ b_hh,
    ushort* __restrict__ Wq_bf, ushort* __restrict__ Wcomb,
    float* __restrict__ bias_p, ushort* __restrict__ X0,
    float* __restrict__ c, float* __restrict__ sT)
{
  int g = blockIdx.x * 256 + threadIdx.x;        // 0 .. 4M-1
  int n = g >> 10, k = g & 1023;
  int np = permrow(n);
  Wq_bf[(size_t)np * 1024 + k] = f2bf(W_ih[(size_t)n * 2048 + k]);
  Wcomb[(size_t)np * 1088 + k] = f2bf(W_hh[(size_t)n * 1024 + k]);
  if (g < 1024 * 1024) {
    X0[(size_t)(g >> 10) * 1088 + (g & 1023)] = f2bf(query[g]);
    c[g] = 0.f;
  }
  if (g < 4096) bias_p[permrow(g)] = b_ih[g] + b_hh[g];
  if (g < 65536) { int kk = g >> 6, s = g & 63; sT[g] = support[(size_t)s * 1024 + kk]; }
}

// SW^T: Wcomb[perm(n)][1024+s] = sum_k support[s][k] * W_ih[n][1024+k]
__global__ __launch_bounds__(256) void sw_kernel(
    const float* __restrict__ sT, const float* __restrict__ W_ih,
    ushort* __restrict__ Wcomb)
{
  int g = blockIdx.x * 256 + threadIdx.x;        // 0..262143
  int n = g >> 6, s = g & 63;                    // n wave-uniform
  const float* wp = W_ih + (size_t)n * 2048 + 1024;
  float acc = 0.f;
#pragma unroll 8
  for (int k = 0; k < 1024; k++) acc += wp[k] * sT[k * 64 + s];
  Wcomb[(size_t)permrow(n) * 1088 + 1024 + s] = f2bf(acc);
}

// ---------------- per-step attention ---------------------------------------
// reads h (bf16) from X[:, :1024], writes softmax(h@support^T) bf16 to X[:,1024:]
__global__ __launch_bounds__(256) void attn_kernel(
    const ushort* __restrict__ Xh, const float* __restrict__ sT,
    ushort* __restrict__ Xa)
{
  __shared__ float hs[2][1024];
  __shared__ float part[4][2][64];
  int t = threadIdx.x;
  int b0 = blockIdx.x * 2;
  {
    int r = t >> 7, c8 = (t & 127) << 3;
    ushort8 v = *(const ushort8*)&Xh[(size_t)(b0 + r) * 1088 + c8];
#pragma unroll
    for (int i = 0; i < 8; i++) hs[r][c8 + i] = bf2f(v[i]);
  }
  __syncthreads();
  int s = t & 63, q = t >> 6;
  const float* st = sT + (size_t)q * 256 * 64 + s;
  const float* h0 = &hs[0][q * 256];
  const float* h1 = &hs[1][q * 256];
  float a0 = 0.f, a1 = 0.f;
#pragma unroll 8
  for (int k = 0; k < 256; k++) {
    float sv = st[(size_t)k * 64];
    a0 += h0[k] * sv; a1 += h1[k] * sv;
  }
  part[q][0][s] = a0; part[q][1][s] = a1;
  __syncthreads();
  if (t < 64) {
#pragma unroll
    for (int r = 0; r < 2; r++) {
      float v = part[0][r][t] + part[1][r][t] + part[2][r][t] + part[3][r][t];
      float m = v;
      for (int off = 32; off; off >>= 1) m = fmaxf(m, __shfl_xor(m, off));
      float e = __expf(v - m);
      float sm = e;
      for (int off = 32; off; off >>= 1) sm += __shfl_xor(sm, off);
      Xa[(size_t)(b0 + r) * 1088 + 1024 + t] = f2bf(e / sm);
    }
  }
}

// ---------------- GEMM (dbuf prefetch) + fused LSTM epilogue ----------------
// mode0 (base==null): Cout[row][col] = acc + bias[col]
// mode1: fused LSTM; writes c, Xout h-part (bf16), optional f32 out
__global__ __launch_bounds__(256) void gemm_step(
    const ushort* __restrict__ A, const ushort* __restrict__ Bw,
    int lda, int ldb, int K,
    const float* __restrict__ base, const float* __restrict__ bias,
    float* __restrict__ Cout,
    float* __restrict__ cbuf, const float* __restrict__ query,
    ushort* __restrict__ Xout, float* __restrict__ outp)
{
  __shared__ ushort As[2][128 * 32];
  __shared__ ushort Bs[2][128 * 32];
  const int t = threadIdx.x;
  // XCD-chunked swizzle: each XCD owns 4 consecutive n-block-cols (L2 locality)
  const int bid = blockIdx.x;
  const int g8 = bid & 7, rr = bid >> 3;
  const int by = g8 * 4 + (rr >> 3), bx = rr & 7;
  const int m0 = bx * 128, n0 = by * 128;
  const int w = t >> 6, l = t & 63;
  const int wm = (w >> 1) * 64, wn = (w & 1) * 64;
  const int srow = t >> 2, scol = (t & 3) * 8;
  const ushort* ga0 = A + (size_t)(m0 + srow) * lda + scol;
  const ushort* ga1 = A + (size_t)(m0 + 64 + srow) * lda + scol;
  const ushort* gb0 = Bw + (size_t)(n0 + srow) * ldb + scol;
  const ushort* gb1 = Bw + (size_t)(n0 + 64 + srow) * ldb + scol;
  const int fr = l & 15, fk = (l >> 4) * 8, fq = l >> 4;
  f32x4 acc[4][4] = {};
  const int nt = K >> 5;
  // prologue: stage tile 0 into buf 0
  async16(&As[0][t * 8], ga0); async16(&As[0][2048 + t * 8], ga1);
  async16(&Bs[0][t * 8], gb0); async16(&Bs[0][2048 + t * 8], gb1);
  __syncthreads();
  for (int it = 0; it < nt; it++) {
    const int cur = it & 1;
    if (it + 1 < nt) {     // prefetch next tile into other buffer
      const int k0 = (it + 1) << 5;
      async16(&As[cur ^ 1][t * 8], ga0 + k0); async16(&As[cur ^ 1][2048 + t * 8], ga1 + k0);
      async16(&Bs[cur ^ 1][t * 8], gb0 + k0); async16(&Bs[cur ^ 1][2048 + t * 8], gb1 + k0);
    }
    const ushort* pa = &As[cur][(wm + fr) * 32 + fk];
    const ushort* pb = &Bs[cur][(wn + fr) * 32 + fk];
    bf16x8 af[4], bfv[4];
#pragma unroll
    for (int mi = 0; mi < 4; mi++) af[mi] = *(const bf16x8*)(pa + mi * 512);
#pragma unroll
    for (int ni = 0; ni < 4; ni++) bfv[ni] = *(const bf16x8*)(pb + ni * 512);
#pragma unroll
    for (int mi = 0; mi < 4; mi++)
#pragma unroll
      for (int ni = 0; ni < 4; ni++)
        acc[mi][ni] = __builtin_amdgcn_mfma_f32_16x16x32_bf16(af[mi], bfv[ni], acc[mi][ni], 0, 0, 0);
    __syncthreads();      // drains prefetch (flew during MFMA) + readers done
  }
  if (!base) {            // mode0: plain C = acc + bias
#pragma unroll
    for (int mi = 0; mi < 4; mi++)
#pragma unroll
      for (int ni = 0; ni < 4; ni++) {
        int col = n0 + wn + ni * 16 + fr;
        int row0 = m0 + wm + mi * 16 + fq * 4;
        float bv = bias[col];
#pragma unroll
        for (int jj = 0; jj < 4; jj++)
          Cout[(size_t)(row0 + jj) * 4096 + col] = acc[mi][ni][jj] + bv;
      }
    return;
  }
  // mode1: lane-local LSTM. acc[mi][ni] = gate ni (i,f,g,o) for j = jbase+fr
  const int jbase = (((n0 + wn) >> 6) << 4);
  const int jcol = jbase + fr;
#pragma unroll
  for (int mi = 0; mi < 4; mi++) {
#pragma unroll
    for (int jj = 0; jj < 4; jj++) {
      int row = m0 + wm + mi * 16 + fq * 4 + jj;
      const float* bp = base + (size_t)row * 4096 + (n0 + wn);
      float gi = acc[mi][0][jj] + bp[fr];
      float gf = acc[mi][1][jj] + bp[16 + fr];
      float gg = acc[mi][2][jj] + bp[32 + fr];
      float go = acc[mi][3][jj] + bp[48 + fr];
      size_t cidx = (size_t)row * 1024 + jcol;
      float cv = cbuf[cidx];
      float cn = sigm_(gf) * cv + sigm_(gi) * tanh_(gg);
      float hn = sigm_(go) * tanh_(cn) + query[cidx];
      cbuf[cidx] = cn;
      Xout[(size_t)row * 1088 + jcol] = f2bf(hn);
      if (outp) outp[cidx] = hn;
    }
  }
}

extern "C" void kernel_launch(void* const* d_in, const int* in_sizes, int n_in,
                              void* d_out, int out_size, void* d_ws, size_t ws_size,
                              hipStream_t stream) {
  const float* query   = (const float*)d_in[0];
  const float* support = (const float*)d_in[1];
  const float* W_ih    = (const float*)d_in[2];
  const float* W_hh    = (const float*)d_in[3];
  const float* b_ih    = (const float*)d_in[4];
  const float* b_hh    = (const float*)d_in[5];
  float* out = (float*)d_out;

  char* ws = (char*)d_ws;
  size_t off = 0;
  auto alloc = [&](size_t bytes) {
    void* p = ws + off;
    off += (bytes + 255) & ~(size_t)255;
    return p;
  };
  ushort* Wq_bf  = (ushort*)alloc((size_t)4096 * 1024 * 2);
  ushort* Wcomb  = (ushort*)alloc((size_t)4096 * 1088 * 2);
  float*  bias_p = (float*) alloc((size_t)4096 * 4);
  float*  base   = (float*) alloc((size_t)1024 * 4096 * 4);
  ushort* X0     = (ushort*)alloc((size_t)1024 * 1088 * 2);
  ushort* X1     = (ushort*)alloc((size_t)1024 * 1088 * 2);
  float*  c      = (float*) alloc((size_t)1024 * 1024 * 4);
  float*  sT     = (float*) alloc((size_t)1024 * 64 * 4);

  prep_kernel<<<16384, 256, 0, stream>>>(query, support, W_ih, W_hh, b_ih, b_hh,
                                         Wq_bf, Wcomb, bias_p, X0, c, sT);
  sw_kernel<<<1024, 256, 0, stream>>>(sT, W_ih, Wcomb);
  // base = bf16(q) @ Wq_perm^T + bias_p   (A = X0 h-part)
  gemm_step<<<256, 256, 0, stream>>>(X0, Wq_bf, 1088, 1024, 1024,
                                     nullptr, bias_p, base,
                                     nullptr, nullptr, nullptr, nullptr);
  for (int step = 0; step < 64; step++) {
    ushort* Xc = (step & 1) ? X1 : X0;
    ushort* Xn = (step & 1) ? X0 : X1;
    attn_kernel<<<512, 256, 0, stream>>>(Xc, sT, Xc);
    gemm_step<<<256, 256, 0, stream>>>(Xc, Wcomb, 1088, 1088, 1088,
                                       base, nullptr, nullptr,
                                       c, query, Xn,
                                       (step == 63) ? out : nullptr);
  }
}

// Round 3
// 2176.207 us; speedup vs baseline: 2.1233x; 1.3277x over previous
//
#include <hip/hip_runtime.h>
#include <hip/hip_bf16.h>

// B=1024, F=1024, S=64, 64 steps.
//   base   = q @ Wq_perm^T + (b_ih+b_hh)_perm     (once, f32, permuted cols)
//   Wcomb  = [W_hh | (support@Wr^T)^T]_perm rows  (once, bf16, K=1088)
//   step:  attn cols of X  = softmax(h_bf @ support^T)    (attn_kernel)
//          gates = X @ Wcomb^T + base  -> fused LSTM -> c, h(bf16 into Xnext)
// GEMM: BM=64 x BN=128 tiles -> 512 blocks = 2/CU (wave-level overlap),
// 3-buffer LDS pipeline, depth-2 prefetch, raw s_barrier + counted vmcnt(3).

typedef __attribute__((ext_vector_type(8))) __bf16 bf16x8;
typedef __attribute__((ext_vector_type(4))) float f32x4;
typedef __attribute__((ext_vector_type(8))) unsigned short ushort8;

__device__ __forceinline__ ushort f2bf(float f) {
  union { float f; unsigned int u; } v; v.f = f;
  unsigned int u = v.u;
  u += 0x7FFFu + ((u >> 16) & 1u);   // RNE
  return (ushort)(u >> 16);
}
__device__ __forceinline__ float bf2f(ushort u) {
  union { float f; unsigned int u; } v; v.u = ((unsigned int)u) << 16; return v.f;
}
__device__ __forceinline__ float sigm_(float x) { return 1.f / (1.f + __expf(-x)); }
__device__ __forceinline__ float tanh_(float x) {
  x = fminf(15.f, fmaxf(-15.f, x));
  float e = __expf(2.f * x);
  return (e - 1.f) / (e + 1.f);
}
__device__ __forceinline__ void async16(ushort* lds, const ushort* g) {
  __builtin_amdgcn_global_load_lds(
      (const __attribute__((address_space(1))) void*)g,
      (__attribute__((address_space(3))) void*)lds, 16, 0, 0);
}
__device__ __forceinline__ int permrow(int n) {   // n = gate*1024 + j
  int g = n >> 10, j = n & 1023;
  return ((j >> 4) << 6) | (g << 4) | (j & 15);
}

// ---------------- precompute ------------------------------------------------
__global__ __launch_bounds__(256) void prep_kernel(
    const float* __restrict__ query, const float* __restrict__ support,
    const float* __restrict__ W_ih, const float* __restrict__ W_hh,
    const float* __restrict__ b_ih, const float* __restrict__ b_hh,
    ushort* __restrict__ Wq_bf, ushort* __restrict__ Wcomb,
    float* __restrict__ bias_p, ushort* __restrict__ X0,
    float* __restrict__ c, float* __restrict__ sT)
{
  int g = blockIdx.x * 256 + threadIdx.x;        // 0 .. 4M-1
  int n = g >> 10, k = g & 1023;
  int np = permrow(n);
  Wq_bf[(size_t)np * 1024 + k] = f2bf(W_ih[(size_t)n * 2048 + k]);
  Wcomb[(size_t)np * 1088 + k] = f2bf(W_hh[(size_t)n * 1024 + k]);
  if (g < 1024 * 1024) {
    X0[(size_t)(g >> 10) * 1088 + (g & 1023)] = f2bf(query[g]);
    c[g] = 0.f;
  }
  if (g < 4096) bias_p[permrow(g)] = b_ih[g] + b_hh[g];
  if (g < 65536) { int kk = g >> 6, s = g & 63; sT[g] = support[(size_t)s * 1024 + kk]; }
}

// SW^T: Wcomb[perm(n)][1024+s] = sum_k support[s][k] * W_ih[n][1024+k]
// 4 independent accumulator chains (was latency-bound on one).
__global__ __launch_bounds__(256) void sw_kernel(
    const float* __restrict__ sT, const float* __restrict__ W_ih,
    ushort* __restrict__ Wcomb)
{
  int g = blockIdx.x * 256 + threadIdx.x;        // 0..262143
  int n = g >> 6, s = g & 63;                    // n wave-uniform
  const float* wp = W_ih + (size_t)n * 2048 + 1024;
  const float* sp = sT + s;
  float a0 = 0.f, a1 = 0.f, a2 = 0.f, a3 = 0.f;
#pragma unroll 4
  for (int k = 0; k < 1024; k += 4) {
    a0 += wp[k]     * sp[(size_t)(k)     * 64];
    a1 += wp[k + 1] * sp[(size_t)(k + 1) * 64];
    a2 += wp[k + 2] * sp[(size_t)(k + 2) * 64];
    a3 += wp[k + 3] * sp[(size_t)(k + 3) * 64];
  }
  Wcomb[(size_t)permrow(n) * 1088 + 1024 + s] = f2bf((a0 + a1) + (a2 + a3));
}

// ---------------- per-step attention ---------------------------------------
// reads h (bf16) from X[:, :1024], writes softmax(h@support^T) bf16 to X[:,1024:]
__global__ __launch_bounds__(256) void attn_kernel(
    const ushort* __restrict__ Xh, const float* __restrict__ sT,
    ushort* __restrict__ Xa)
{
  __shared__ float hs[2][1024];
  __shared__ float part[4][2][64];
  int t = threadIdx.x;
  int b0 = blockIdx.x * 2;
  {
    int r = t >> 7, c8 = (t & 127) << 3;
    ushort8 v = *(const ushort8*)&Xh[(size_t)(b0 + r) * 1088 + c8];
#pragma unroll
    for (int i = 0; i < 8; i++) hs[r][c8 + i] = bf2f(v[i]);
  }
  __syncthreads();
  int s = t & 63, q = t >> 6;
  const float* st = sT + (size_t)q * 256 * 64 + s;
  const float* h0 = &hs[0][q * 256];
  const float* h1 = &hs[1][q * 256];
  float a0 = 0.f, a1 = 0.f;
#pragma unroll 8
  for (int k = 0; k < 256; k++) {
    float sv = st[(size_t)k * 64];
    a0 += h0[k] * sv; a1 += h1[k] * sv;
  }
  part[q][0][s] = a0; part[q][1][s] = a1;
  __syncthreads();
  if (t < 64) {
#pragma unroll
    for (int r = 0; r < 2; r++) {
      float v = part[0][r][t] + part[1][r][t] + part[2][r][t] + part[3][r][t];
      float m = v;
      for (int off = 32; off; off >>= 1) m = fmaxf(m, __shfl_xor(m, off));
      float e = __expf(v - m);
      float sm = e;
      for (int off = 32; off; off >>= 1) sm += __shfl_xor(sm, off);
      Xa[(size_t)(b0 + r) * 1088 + 1024 + t] = f2bf(e / sm);
    }
  }
}

// ---------------- GEMM (3-buf depth-2 pipeline) + fused LSTM epilogue -------
// BM=64, BN=128, 256 thr / 4 waves, wave tile 32x64 (2x4 frags).
// mode0 (base==null): Cout[row][col] = acc + bias[col]
// mode1: fused LSTM; writes c, Xout h-part (bf16), optional f32 out
__global__ __launch_bounds__(256) void gemm_step(
    const ushort* __restrict__ A, const ushort* __restrict__ Bw,
    int lda, int ldb, int K,
    const float* __restrict__ base, const float* __restrict__ bias,
    float* __restrict__ Cout,
    float* __restrict__ cbuf, const float* __restrict__ query,
    ushort* __restrict__ Xout, float* __restrict__ outp)
{
  __shared__ ushort As[3][64 * 32];    // 12 KB
  __shared__ ushort Bs[3][128 * 32];   // 24 KB
  const int t = threadIdx.x;
  // 512 blocks; xcd = bid&7 owns 4 consecutive n-block-cols (L2 locality)
  const int bid = blockIdx.x;
  const int xcd = bid & 7, idx = bid >> 3;
  const int bx = idx & 15, byy = idx >> 4;
  const int by = xcd * 4 + byy;
  const int m0 = bx * 64, n0 = by * 128;
  const int w = t >> 6, l = t & 63;
  const int wm = (w >> 1) * 32, wn = (w & 1) * 64;
  const int srow = t >> 2, scol = (t & 3) * 8;
  const ushort* ga  = A  + (size_t)(m0 + srow) * lda + scol;
  const ushort* gb0 = Bw + (size_t)(n0 + srow) * ldb + scol;
  const ushort* gb1 = Bw + (size_t)(n0 + 64 + srow) * ldb + scol;
  const int fr = l & 15, fk = (l >> 4) * 8, fq = l >> 4;
  f32x4 acc[2][4] = {};
  const int nt = K >> 5;   // 3 VMEM instrs per tile
  // prologue: 2 tiles in flight
  {
    async16(&As[0][t * 8], ga);
    async16(&Bs[0][t * 8], gb0);
    async16(&Bs[0][2048 + t * 8], gb1);
    async16(&As[1][t * 8], ga + 32);
    async16(&Bs[1][t * 8], gb0 + 32);
    async16(&Bs[1][2048 + t * 8], gb1 + 32);
  }
  for (int it = 0; it < nt; it++) {
    // wait tile `it` landed: newer tile (it+1) keeps 3 ops in flight
    if (it + 1 < nt) { asm volatile("s_waitcnt vmcnt(3)" ::: "memory"); }
    else             { asm volatile("s_waitcnt vmcnt(0)" ::: "memory"); }
    __builtin_amdgcn_s_barrier();
    __builtin_amdgcn_sched_barrier(0);
    const int b = it % 3;
    const ushort* pa = &As[b][(wm + fr) * 32 + fk];
    const ushort* pb = &Bs[b][(wn + fr) * 32 + fk];
    bf16x8 af[2], bfv[4];
#pragma unroll
    for (int mi = 0; mi < 2; mi++) af[mi] = *(const bf16x8*)(pa + mi * 512);
#pragma unroll
    for (int ni = 0; ni < 4; ni++) bfv[ni] = *(const bf16x8*)(pb + ni * 512);
    if (it + 2 < nt) {   // depth-2 prefetch into the just-freed buffer
      const int pbuf = (it + 2) % 3;
      const int k0 = (it + 2) << 5;
      async16(&As[pbuf][t * 8], ga + k0);
      async16(&Bs[pbuf][t * 8], gb0 + k0);
      async16(&Bs[pbuf][2048 + t * 8], gb1 + k0);
    }
#pragma unroll
    for (int mi = 0; mi < 2; mi++)
#pragma unroll
      for (int ni = 0; ni < 4; ni++)
        acc[mi][ni] = __builtin_amdgcn_mfma_f32_16x16x32_bf16(af[mi], bfv[ni], acc[mi][ni], 0, 0, 0);
  }
  if (!base) {            // mode0: plain C = acc + bias
#pragma unroll
    for (int mi = 0; mi < 2; mi++)
#pragma unroll
      for (int ni = 0; ni < 4; ni++) {
        int col = n0 + wn + ni * 16 + fr;
        int row0 = m0 + wm + mi * 16 + fq * 4;
        float bv = bias[col];
#pragma unroll
        for (int jj = 0; jj < 4; jj++)
          Cout[(size_t)(row0 + jj) * 4096 + col] = acc[mi][ni][jj] + bv;
      }
    return;
  }
  // mode1: lane-local LSTM. acc[mi][ni] = gate ni (i,f,g,o) for j = jbase+fr
  const int jbase = (((n0 + wn) >> 6) << 4);
  const int jcol = jbase + fr;
#pragma unroll
  for (int mi = 0; mi < 2; mi++) {
#pragma unroll
    for (int jj = 0; jj < 4; jj++) {
      int row = m0 + wm + mi * 16 + fq * 4 + jj;
      const float* bp = base + (size_t)row * 4096 + (n0 + wn);
      float gi = acc[mi][0][jj] + bp[fr];
      float gf = acc[mi][1][jj] + bp[16 + fr];
      float gg = acc[mi][2][jj] + bp[32 + fr];
      float go = acc[mi][3][jj] + bp[48 + fr];
      size_t cidx = (size_t)row * 1024 + jcol;
      float cv = cbuf[cidx];
      float cn = sigm_(gf) * cv + sigm_(gi) * tanh_(gg);
      float hn = sigm_(go) * tanh_(cn) + query[cidx];
      cbuf[cidx] = cn;
      Xout[(size_t)row * 1088 + jcol] = f2bf(hn);
      if (outp) outp[cidx] = hn;
    }
  }
}

extern "C" void kernel_launch(void* const* d_in, const int* in_sizes, int n_in,
                              void* d_out, int out_size, void* d_ws, size_t ws_size,
                              hipStream_t stream) {
  const float* query   = (const float*)d_in[0];
  const float* support = (const float*)d_in[1];
  const float* W_ih    = (const float*)d_in[2];
  const float* W_hh    = (const float*)d_in[3];
  const float* b_ih    = (const float*)d_in[4];
  const float* b_hh    = (const float*)d_in[5];
  float* out = (float*)d_out;

  char* ws = (char*)d_ws;
  size_t off = 0;
  auto alloc = [&](size_t bytes) {
    void* p = ws + off;
    off += (bytes + 255) & ~(size_t)255;
    return p;
  };
  ushort* Wq_bf  = (ushort*)alloc((size_t)4096 * 1024 * 2);
  ushort* Wcomb  = (ushort*)alloc((size_t)4096 * 1088 * 2);
  float*  bias_p = (float*) alloc((size_t)4096 * 4);
  float*  base   = (float*) alloc((size_t)1024 * 4096 * 4);
  ushort* X0     = (ushort*)alloc((size_t)1024 * 1088 * 2);
  ushort* X1     = (ushort*)alloc((size_t)1024 * 1088 * 2);
  float*  c      = (float*) alloc((size_t)1024 * 1024 * 4);
  float*  sT     = (float*) alloc((size_t)1024 * 64 * 4);

  prep_kernel<<<16384, 256, 0, stream>>>(query, support, W_ih, W_hh, b_ih, b_hh,
                                         Wq_bf, Wcomb, bias_p, X0, c, sT);
  sw_kernel<<<1024, 256, 0, stream>>>(sT, W_ih, Wcomb);
  // base = bf16(q) @ Wq_perm^T + bias_p   (A = X0 h-part)
  gemm_step<<<512, 256, 0, stream>>>(X0, Wq_bf, 1088, 1024, 1024,
                                     nullptr, bias_p, base,
                                     nullptr, nullptr, nullptr, nullptr);
  for (int step = 0; step < 64; step++) {
    ushort* Xc = (step & 1) ? X1 : X0;
    ushort* Xn = (step & 1) ? X0 : X1;
    attn_kernel<<<512, 256, 0, stream>>>(Xc, sT, Xc);
    gemm_step<<<512, 256, 0, stream>>>(Xc, Wcomb, 1088, 1088, 1088,
                                       base, nullptr, nullptr,
                                       c, query, Xn,
                                       (step == 63) ? out : nullptr);
  }
}